// Round 13
// baseline (6036.398 us; speedup 1.0000x reference)
//
#include <hip/hip_runtime.h>
#include <math.h>
#include <stdint.h>

#define B 128
#define S 512
#define V 6000
#define E 100
#define H 256
#define G4 1024   /* 4*H */
#define T 9

/* W column split: 64 float4 k-groups per gate row.
   Groups [0,3) live in static LDS (48 KB). The remaining 61 groups are
   streamed; template param NROW = how many of them are loaded row-major
   in-loop from whh (uncoalesced, L2-hit) vs k-major coalesced from wstr.
   FULL layout: NROW=0 (all 61 coalesced). Fallback: NROW=20 (R9 config). */
#define GLDS 3

/* workspace byte offsets (256-aligned) */
#define OFF_PEMB_F 0u
#define PEMB_BYTES (V*G4*4u)                    /* 24,576,000 */
#define OFF_PEMB_B (OFF_PEMB_F + PEMB_BYTES)
#define OFF_EMF    (OFF_PEMB_B + PEMB_BYTES)    /* 49,152,000 */
#define EM_BYTES   (B*S*T*4u)                   /* 2,359,296 */
#define OFF_EMB    (OFF_EMF + EM_BYTES)
#define OFF_BP     (OFF_EMB + EM_BYTES)         /* 53,870,592 */
#define BP_BYTES   ((S-1)*B*16u)                /* 1,046,528 */
#define OFF_LT     (OFF_BP + BP_BYTES)          /* 54,917,120 */
#define OFF_PT     (OFF_LT + 512u)              /* 54,917,632 */
#define PT_BYTES   (B*S*4u)                     /* 262,144 */
#define OFF_WFULL  (OFF_PT + PT_BYTES)          /* 55,179,776 */
#define WFULL_BYTES (2ull*61*1024*16)           /* 1,998,848 -> end 57,178,624 */

__device__ __forceinline__ float sigf(float x) { return 1.0f / (1.0f + expf(-x)); }

/* pemb[v][g4] = bias[g4] + sum_e emb[v][e] * W_ih[g4][e],  g4 = q*H + j */
__global__ __launch_bounds__(256) void k_pemb(const float* __restrict__ emb,
                                              const float* __restrict__ wf, const float* __restrict__ bf,
                                              const float* __restrict__ wb, const float* __restrict__ bb,
                                              char* __restrict__ ws) {
    int blk = blockIdx.x;                   /* 0..749 */
    int d   = blk >= 375;
    int vb  = d ? blk - 375 : blk;
    const float* W    = d ? wb : wf;
    const float* bias = d ? bb : bf;
    float* pe = (float*)(ws + (d ? OFF_PEMB_B : OFF_PEMB_F));

    __shared__ float es[16 * E];
    for (int i = threadIdx.x; i < 16 * E; i += 256) es[i] = emb[vb * 16 * E + i];
    __syncthreads();

    int j = threadIdx.x;
    float acc[4][16];
    #pragma unroll
    for (int q = 0; q < 4; q++) {
        float bq = bias[q * H + j];
        #pragma unroll
        for (int v = 0; v < 16; v++) acc[q][v] = bq;
    }
    for (int e = 0; e < E; e++) {
        float w0 = W[(0 * H + j) * E + e];
        float w1 = W[(1 * H + j) * E + e];
        float w2 = W[(2 * H + j) * E + e];
        float w3 = W[(3 * H + j) * E + e];
        #pragma unroll
        for (int v = 0; v < 16; v++) {
            float x = es[v * E + e];
            acc[0][v] += w0 * x; acc[1][v] += w1 * x;
            acc[2][v] += w2 * x; acc[3][v] += w3 * x;
        }
    }
    for (int v = 0; v < 16; v++)
        #pragma unroll
        for (int q = 0; q < 4; q++)
            pe[(vb * 16 + v) * G4 + q * H + j] = acc[q][v];
}

/* k-major streamed-W: wstr[(d*nstr + gi)*1024 + r] = W_d[r][4*(colbase+gi)..+3]
   -> in k_lstm, lane r loads consecutive float4: one 64B-line per 4 lanes. */
__global__ __launch_bounds__(256) void k_prep2(const float* __restrict__ whhf,
                                               const float* __restrict__ whhb,
                                               float4* __restrict__ wstr,
                                               int colbase, int nstr) {
    int tid = blockIdx.x * 256 + threadIdx.x;
    if (tid >= 2 * nstr * 1024) return;
    int d   = tid >= nstr * 1024;
    int idx = d ? tid - nstr * 1024 : tid;
    int gi = idx >> 10, r = idx & 1023;
    const float* whh = d ? whhb : whhf;
    wstr[((size_t)(d * nstr + gi) << 10) + r] =
        ((const float4*)(whh + (size_t)r * H))[colbase + gi];
}

/* Single-CU LSTM: 256 blocks (dir d = blk>>7, batch b = blk&127) x 512 thr.
   Thread t owns gate rows t, t+512. W per row: 3 groups static LDS,
   NROW groups row-major in-loop (fallback only), NSTR=61-NROW groups
   k-major coalesced from wstr. R12 lesson: AGPR transport costs VALU issue
   -> dropped. New: ALL streamed loads coalesced (R9 carried 20 row-major
   groups = 4x L2-line amplification), + 2-group software pipeline across
   the barrier (stream data is step-invariant; reload after last use so the
   TA pipe stays busy through activation/emission). */
template<int NROW>
__global__ __launch_bounds__(512, 2) void k_lstm_t(const int* __restrict__ data,
                                                   const float* __restrict__ whhf,
                                                   const float* __restrict__ whhb,
                                                   const float* __restrict__ mlpW,
                                                   const float4* __restrict__ wstrAll,
                                                   char* __restrict__ ws) {
    constexpr int NSTR = 61 - NROW;
    int blk = blockIdx.x;
    int d = blk >> 7, b = blk & 127;
    const float* whh = d ? whhb : whhf;
    const float* pe  = (const float*)(ws + (d ? OFF_PEMB_B : OFF_PEMB_F));
    float* emdst = (float*)(ws + (d ? OFF_EMB : OFF_EMF));
    const float4* wstrD = wstrAll + ((size_t)(d * NSTR) << 10);

    __shared__ __align__(16) float hs[H];      /* h_prev, 1 KB */
    __shared__ float4 sW[GLDS << 10];          /* 48 KB */
    __shared__ float  gbuf[G4];                /* 4 KB */
    __shared__ float  red[T][4];
    __shared__ int    toks[S];                 /* 2 KB */

    int t = threadIdx.x;                       /* 0..511 */
    int r0 = t, r1 = t + 512;
    const float4* wrow0 = (const float4*)(whh + (size_t)r0 * H);
    const float4* wrow1 = (const float4*)(whh + (size_t)r1 * H);

    #pragma unroll
    for (int g = 0; g < GLDS; g++) {
        sW[(g << 10) + r0] = wrow0[g];
        sW[(g << 10) + r1] = wrow1[g];
    }
    toks[t] = data[b * S + t];                 /* S == 512 == blockDim */

    float mw[T];
    if (t < 256) {
        #pragma unroll
        for (int tt = 0; tt < T; tt++) mw[tt] = mlpW[tt * (2 * H) + d * H + t];
    }
    if (t < H) hs[t] = 0.0f;
    float cst = 0.0f;
    __syncthreads();

    const float4* hs4 = (const float4*)hs;
    const float4* wsp0 = wstrD + r0;
    const float4* wsp1 = wstrD + r1;

    float pf0, pf1;
    {
        int sp0 = d ? (S - 1) : 0;
        size_t tok = (size_t)toks[sp0];
        pf0 = pe[(tok << 10) + r0];
        pf1 = pe[(tok << 10) + r1];
    }
    /* held stream groups 0,1 (software pipeline across the barrier) */
    float4 n00 = wsp0[0],        n10 = wsp1[0];
    float4 n01 = wsp0[1 << 10],  n11 = wsp1[1 << 10];

    for (int ss = 0; ss < S; ss++) {
        int sp = d ? (S - 1 - ss) : ss;
        float acc0 = pf0, acc1 = pf1;
        if (ss + 1 < S) {
            int spn = d ? (S - 2 - ss) : (ss + 1);
            size_t tok = (size_t)toks[spn];
            pf0 = pe[(tok << 10) + r0];
            pf1 = pe[(tok << 10) + r1];
        }

        /* LDS phase: col-groups [0,3) */
        #pragma unroll
        for (int g = 0; g < GLDS; g++) {
            float4 w0 = sW[(g << 10) + r0];
            float4 w1 = sW[(g << 10) + r1];
            float4 h4 = hs4[g];
            acc0 = fmaf(w0.x, h4.x, acc0);  acc1 = fmaf(w1.x, h4.x, acc1);
            acc0 = fmaf(w0.y, h4.y, acc0);  acc1 = fmaf(w1.y, h4.y, acc1);
            acc0 = fmaf(w0.z, h4.z, acc0);  acc1 = fmaf(w1.z, h4.z, acc1);
            acc0 = fmaf(w0.w, h4.w, acc0);  acc1 = fmaf(w1.w, h4.w, acc1);
        }
        /* row-major phase (fallback layout only; NROW=0 in full layout) */
        #pragma unroll
        for (int g = 0; g < NROW; g++) {
            float4 w0 = wrow0[GLDS + g];
            float4 w1 = wrow1[GLDS + g];
            float4 h4 = hs4[GLDS + g];
            acc0 = fmaf(w0.x, h4.x, acc0);  acc1 = fmaf(w1.x, h4.x, acc1);
            acc0 = fmaf(w0.y, h4.y, acc0);  acc1 = fmaf(w1.y, h4.y, acc1);
            acc0 = fmaf(w0.z, h4.z, acc0);  acc1 = fmaf(w1.z, h4.z, acc1);
            acc0 = fmaf(w0.w, h4.w, acc0);  acc1 = fmaf(w1.w, h4.w, acc1);
        }
        /* streamed phase: gs=0,1 from held regs */
        {
            float4 h4 = hs4[GLDS + NROW];
            acc0 = fmaf(n00.x, h4.x, acc0);  acc1 = fmaf(n10.x, h4.x, acc1);
            acc0 = fmaf(n00.y, h4.y, acc0);  acc1 = fmaf(n10.y, h4.y, acc1);
            acc0 = fmaf(n00.z, h4.z, acc0);  acc1 = fmaf(n10.z, h4.z, acc1);
            acc0 = fmaf(n00.w, h4.w, acc0);  acc1 = fmaf(n10.w, h4.w, acc1);
            h4 = hs4[GLDS + NROW + 1];
            acc0 = fmaf(n01.x, h4.x, acc0);  acc1 = fmaf(n11.x, h4.x, acc1);
            acc0 = fmaf(n01.y, h4.y, acc0);  acc1 = fmaf(n11.y, h4.y, acc1);
            acc0 = fmaf(n01.z, h4.z, acc0);  acc1 = fmaf(n11.z, h4.z, acc1);
            acc0 = fmaf(n01.w, h4.w, acc0);  acc1 = fmaf(n11.w, h4.w, acc1);
        }
        /* streamed phase: gs=2..NSTR-1, coalesced k-major loads */
        #pragma unroll 4
        for (int gs = 2; gs < NSTR; gs++) {
            float4 w0 = wsp0[(size_t)gs << 10];
            float4 w1 = wsp1[(size_t)gs << 10];
            float4 h4 = hs4[GLDS + NROW + gs];
            acc0 = fmaf(w0.x, h4.x, acc0);  acc1 = fmaf(w1.x, h4.x, acc1);
            acc0 = fmaf(w0.y, h4.y, acc0);  acc1 = fmaf(w1.y, h4.y, acc1);
            acc0 = fmaf(w0.z, h4.z, acc0);  acc1 = fmaf(w1.z, h4.z, acc1);
            acc0 = fmaf(w0.w, h4.w, acc0);  acc1 = fmaf(w1.w, h4.w, acc1);
        }
        /* reload held pair for NEXT step (constant data, no deps) -- the
           loads drain during activation/emission instead of stalling the
           next FMA phase */
        n00 = wsp0[0];        n10 = wsp1[0];
        n01 = wsp0[1 << 10];  n11 = wsp1[1 << 10];

        gbuf[r0] = acc0;
        gbuf[r1] = acc1;
        __syncthreads();   /* B1: gates complete, hs reads done */

        if (t < 256) {
            float gi = gbuf[t], gf = gbuf[H + t], gg = gbuf[2 * H + t], go = gbuf[3 * H + t];
            float ig = sigf(gi), fg = sigf(gf), tg = tanhf(gg), og = sigf(go);
            cst = fg * cst + ig * tg;
            float hn = og * tanhf(cst);
            hs[t] = hn;
            int l = t & 63, wv = t >> 6;
            #pragma unroll
            for (int tt = 0; tt < T; tt++) {
                float v = hn * mw[tt];
                v += __shfl_xor(v, 32, 64); v += __shfl_xor(v, 16, 64);
                v += __shfl_xor(v, 8, 64);  v += __shfl_xor(v, 4, 64);
                v += __shfl_xor(v, 2, 64);  v += __shfl_xor(v, 1, 64);
                if (l == 0) red[tt][wv] = v;
            }
        }
        __syncthreads();   /* B2: hs updated + red ready */
        if (t < T)
            emdst[((size_t)b * S + sp) * T + t] = red[t][0] + red[t][1] + red[t][2] + red[t][3];
    }
}

/* Viterbi forward: one wave per batch, lane t = tag. Strict-> ascending scan
   matches jnp.argmax first-index tie-breaking. */
__global__ __launch_bounds__(64) void k_vit(const int* __restrict__ data,
                                            const float* __restrict__ strans,
                                            const float* __restrict__ trans,
                                            const float* __restrict__ etrans,
                                            const float* __restrict__ mlpb,
                                            float* __restrict__ out,
                                            char* __restrict__ ws) {
    int b = blockIdx.x, t = threadIdx.x;
    const float* emf = (const float*)(ws + OFF_EMF);
    const float* emb = (const float*)(ws + OFF_EMB);
    char* bp = ws + OFF_BP;
    int*  lt = (int*)(ws + OFF_LT);
    bool act = t < T;

    float trp[T];
    float mb = 0.0f;
    if (act) {
        #pragma unroll
        for (int p = 0; p < T; p++) trp[p] = trans[p * T + t];
        mb = mlpb[t];
    }
    float score = -1e30f;
    if (act) score = strans[t] + emf[(b * S) * T + t] + emb[(b * S) * T + t] + mb;

    for (int s = 1; s < S; s++) {
        float e = 0.0f;
        if (act) e = emf[(b * S + s) * T + t] + emb[(b * S + s) * T + t] + mb;
        float best = __shfl(score, 0, 64) + trp[0];
        int bpi = 0;
        #pragma unroll
        for (int p = 1; p < T; p++) {
            float cand = __shfl(score, p, 64) + trp[p];
            if (cand > best) { best = cand; bpi = p; }
        }
        int m = data[b * S + s] != 0;
        if (act) {
            score = m ? (best + e) : score;
            bp[((size_t)(s - 1) * B + b) * 16 + t] = (char)bpi;
        }
    }
    float fin = act ? score + etrans[t] : -1e30f;
    float bv = __shfl(fin, 0, 64);
    int bi = 0;
    #pragma unroll
    for (int p = 1; p < T; p++) {
        float v = __shfl(fin, p, 64);
        if (v > bv) { bv = v; bi = p; }
    }
    if (t == 0) { out[B * S + b] = bv; lt[b] = bi; }
}

/* Backtrack: thread = batch; bp row address is tag-independent -> pipelined loads */
__global__ __launch_bounds__(128) void k_back(const int* __restrict__ data, char* __restrict__ ws) {
    int b = threadIdx.x;
    const int4* bp4 = (const int4*)(ws + OFF_BP);
    const int*  lt  = (const int*)(ws + OFF_LT);
    int* pt = (int*)(ws + OFF_PT);
    int tag = lt[b];
    pt[(S - 1) * B + b] = tag;
    for (int p = S - 2; p >= 0; p--) {
        int4 r = bp4[(size_t)p * B + b];
        int m = data[b * S + p + 1] != 0;
        unsigned w = (unsigned)(tag < 8 ? (tag < 4 ? r.x : r.y) : r.z);
        int nt = (int)((w >> ((tag & 3) * 8)) & 0xff);
        tag = m ? nt : tag;
        pt[p * B + b] = tag;
    }
}

/* paths -> float output with mask zeroing */
__global__ __launch_bounds__(256) void k_fin(const int* __restrict__ data,
                                             float* __restrict__ out,
                                             const char* __restrict__ ws) {
    int tid = blockIdx.x * 256 + threadIdx.x;   /* 65536 */
    const int* pt = (const int*)(ws + OFF_PT);
    int b = tid >> 9, p = tid & 511;
    out[tid] = (data[tid] != 0) ? (float)pt[p * B + b] : 0.0f;
}

extern "C" void kernel_launch(void* const* d_in, const int* in_sizes, int n_in,
                              void* d_out, int out_size, void* d_ws, size_t ws_size,
                              hipStream_t stream) {
    const int*   data = (const int*)d_in[0];
    /* d_in[1] = mask (bool) — unused; mask == (data != 0) */
    const float* emb  = (const float*)d_in[2];
    const float* wihf = (const float*)d_in[3];
    const float* whhf = (const float*)d_in[4];
    const float* bf   = (const float*)d_in[5];
    const float* wihb = (const float*)d_in[6];
    const float* whhb = (const float*)d_in[7];
    const float* bb   = (const float*)d_in[8];
    const float* mlpW = (const float*)d_in[9];
    const float* mlpb = (const float*)d_in[10];
    const float* st   = (const float*)d_in[11];
    const float* tr   = (const float*)d_in[12];
    const float* et   = (const float*)d_in[13];
    float* out = (float*)d_out;
    char*  ws  = (char*)d_ws;

    /* Layout choice is a pure function of ws_size (constant per session) ->
       identical work every call, graph-capture safe.
       FULL: all 61 streamed groups k-major at OFF_WFULL (needs ~57.2 MB).
       FALLBACK (= R9 layout): 41 k-major in the BP overlay + 20 row-major. */
    bool full = ws_size >= (size_t)OFF_WFULL + (size_t)WFULL_BYTES;
    float4* wstr = full ? (float4*)(ws + OFF_WFULL) : (float4*)(ws + OFF_BP);
    int nrow = full ? 0 : 20;
    int nstr = 61 - nrow;
    int prep_blocks = (2 * nstr * 1024 + 255) / 256;

    k_pemb<<<dim3(750), dim3(256), 0, stream>>>(emb, wihf, bf, wihb, bb, ws);
    k_prep2<<<dim3(prep_blocks), dim3(256), 0, stream>>>(whhf, whhb, wstr, GLDS + nrow, nstr);
    if (full)
        k_lstm_t<0><<<dim3(256), dim3(512), 0, stream>>>(data, whhf, whhb, mlpW, wstr, ws);
    else
        k_lstm_t<20><<<dim3(256), dim3(512), 0, stream>>>(data, whhf, whhb, mlpW, wstr, ws);
    k_vit<<<dim3(128), dim3(64), 0, stream>>>(data, st, tr, et, mlpb, out, ws);
    k_back<<<dim3(1), dim3(128), 0, stream>>>(data, ws);
    k_fin<<<dim3(256), dim3(256), 0, stream>>>(data, out, ws);
}

// Round 14
// 4776.250 us; speedup vs baseline: 1.2638x; 1.2638x over previous
//
#include <hip/hip_runtime.h>
#include <math.h>
#include <stdint.h>

#define B 128
#define S 512
#define V 6000
#define E 100
#define H 256
#define G4 1024   /* 4*H */
#define T 9

/* W column split (float4 k-groups, 64 total = 256 cols per row) */
#define WREG 20            /* cols [0,80)  "pinned": forces ~160 live load results
                              = deep load pipeline (the actual R9 win; see R13) */
#define WLDS 3             /* cols [80,92) in LDS slab (48 KB) */
#define WSTR 41            /* cols [92,256) streamed k-major (656 KB/step/dir) */

/* workspace byte offsets (256-aligned) */
#define OFF_PEMB_F 0u
#define PEMB_BYTES (V*G4*4u)                    /* 24,576,000 */
#define OFF_PEMB_B (OFF_PEMB_F + PEMB_BYTES)
#define OFF_EMF    (OFF_PEMB_B + PEMB_BYTES)    /* 49,152,000 */
#define EM_BYTES   (B*S*T*4u)                   /* 2,359,296 */
#define OFF_EMB    (OFF_EMF + EM_BYTES)
#define OFF_BP     (OFF_EMB + EM_BYTES)         /* 53,870,592 */
#define BP_BYTES   ((S-1)*B*16u)                /* 1,046,528 */
#define OFF_LT     (OFF_BP + BP_BYTES)
#define OFF_PT     (OFF_LT + 512u)
/* Streamed-W (2 dirs x 41 groups x 1024 rows x 16 B = 1,343,488 B) OVERLAYS
   the BP/LT/PT region: k_prep writes it and k_lstm reads it strictly BEFORE
   k_vit/k_back write BP/LT/PT (stream-ordered). */
#define OFF_WSTREAM OFF_BP

__device__ __forceinline__ float sigf(float x) { return 1.0f / (1.0f + expf(-x)); }

/* pemb[v][g4] = bias[g4] + sum_e emb[v][e] * W_ih[g4][e],  g4 = q*H + j */
__global__ __launch_bounds__(256) void k_pemb(const float* __restrict__ emb,
                                              const float* __restrict__ wf, const float* __restrict__ bf,
                                              const float* __restrict__ wb, const float* __restrict__ bb,
                                              char* __restrict__ ws) {
    int blk = blockIdx.x;                   /* 0..749 */
    int d   = blk >= 375;
    int vb  = d ? blk - 375 : blk;
    const float* W    = d ? wb : wf;
    const float* bias = d ? bb : bf;
    float* pe = (float*)(ws + (d ? OFF_PEMB_B : OFF_PEMB_F));

    __shared__ float es[16 * E];
    for (int i = threadIdx.x; i < 16 * E; i += 256) es[i] = emb[vb * 16 * E + i];
    __syncthreads();

    int j = threadIdx.x;
    float acc[4][16];
    #pragma unroll
    for (int q = 0; q < 4; q++) {
        float bq = bias[q * H + j];
        #pragma unroll
        for (int v = 0; v < 16; v++) acc[q][v] = bq;
    }
    for (int e = 0; e < E; e++) {
        float w0 = W[(0 * H + j) * E + e];
        float w1 = W[(1 * H + j) * E + e];
        float w2 = W[(2 * H + j) * E + e];
        float w3 = W[(3 * H + j) * E + e];
        #pragma unroll
        for (int v = 0; v < 16; v++) {
            float x = es[v * E + e];
            acc[0][v] += w0 * x; acc[1][v] += w1 * x;
            acc[2][v] += w2 * x; acc[3][v] += w3 * x;
        }
    }
    for (int v = 0; v < 16; v++)
        #pragma unroll
        for (int q = 0; q < 4; q++)
            pe[(vb * 16 + v) * G4 + q * H + j] = acc[q][v];
}

/* streamed-W layout: wstr[(d*WSTR + g)*1024 + r] = {W_d[r][92+4g .. +3]}
   -> per step, lane r loads consecutive float4 (coalesced 1 KB/wave-inst) */
__global__ __launch_bounds__(256) void k_prep(const float* __restrict__ whhf,
                                              const float* __restrict__ whhb,
                                              char* __restrict__ ws) {
    int tid = blockIdx.x * 256 + threadIdx.x;   /* 2*41*1024 = 83968 */
    if (tid >= 2 * WSTR * 1024) return;
    int d   = tid >= WSTR * 1024;
    int idx = d ? tid - WSTR * 1024 : tid;
    int g = idx >> 10, r = idx & 1023;
    const float* whh = d ? whhb : whhf;
    float4* wstr = (float4*)(ws + OFF_WSTREAM);
    const float4* src = (const float4*)(whh + (size_t)r * H + 4 * (WREG + WLDS));
    wstr[((size_t)(d * WSTR + g) << 10) + r] = src[g];
}

/* Single-CU LSTM: 256 blocks (dir d = blk>>7, batch b = blk&127) x 512 thr.
   Thread t owns gate rows t and t+512. Per row: cols [0,80) asm-pinned loads
   (the pin forces ~160 live load results -> deep pipeline; removing it
   collapsed VGPR to 52 and cost +2.8us/step, R13), [80,92) in LDS,
   [92,256) streamed coalesced from L2 (656 KB/step, k-major).
   This is the empirical optimum of 6 measured variants (R7-R13):
   the step overlaps ~5.7us W-stream + ~3us LDS-broadcast issue + ~3us VALU
   + 2 barrier drains -> 8.8us/step knee. */
__global__ __attribute__((amdgpu_flat_work_group_size(512, 512), amdgpu_waves_per_eu(2, 2)))
void k_lstm(const int* __restrict__ data,
            const float* __restrict__ whhf,
            const float* __restrict__ whhb,
            const float* __restrict__ mlpW,
            char* __restrict__ ws) {
    int blk = blockIdx.x;
    int d = blk >> 7, b = blk & 127;
    const float* whh = d ? whhb : whhf;
    const float* pe  = (const float*)(ws + (d ? OFF_PEMB_B : OFF_PEMB_F));
    float* emdst = (float*)(ws + (d ? OFF_EMB : OFF_EMF));
    const float4* wstr = (const float4*)(ws + OFF_WSTREAM) + ((size_t)(d * WSTR) << 10);

    __shared__ __align__(16) float hs[H];      /* h_prev, 1 KB */
    __shared__ float4 sW[WLDS << 10];          /* 48 KB */
    __shared__ float  gbuf[G4];                /* 4 KB */
    __shared__ float  red[T][4];
    __shared__ int    toks[S];                 /* 2 KB */

    int t = threadIdx.x;                       /* 0..511 */
    int r0 = t, r1 = t + 512;

    const float4* wrow0 = (const float4*)(whh + (size_t)r0 * H);
    const float4* wrow1 = (const float4*)(whh + (size_t)r1 * H);
    float4 wA[WREG], wB[WREG];
    #pragma unroll
    for (int g = 0; g < WREG; g++) { wA[g] = wrow0[g]; wB[g] = wrow1[g]; }
    /* pin: consume the loads pre-loop; keeps a ~160-reg load pipeline live */
    #pragma unroll
    for (int g = 0; g < WREG; g++) {
        asm volatile("" : "+v"(wA[g].x), "+v"(wA[g].y), "+v"(wA[g].z), "+v"(wA[g].w));
        asm volatile("" : "+v"(wB[g].x), "+v"(wB[g].y), "+v"(wB[g].z), "+v"(wB[g].w));
    }
    #pragma unroll
    for (int g = 0; g < WLDS; g++) {
        sW[(g << 10) + r0] = wrow0[WREG + g];
        sW[(g << 10) + r1] = wrow1[WREG + g];
    }

    toks[t] = data[b * S + t];                 /* S == 512 == blockDim */

    float mw[T];
    if (t < 256) {
        #pragma unroll
        for (int tt = 0; tt < T; tt++) mw[tt] = mlpW[tt * (2 * H) + d * H + t];
    }
    if (t < H) hs[t] = 0.0f;
    float cst = 0.0f;
    __syncthreads();

    const float4* hs4 = (const float4*)hs;
    const float4* wsp0 = wstr + r0;
    const float4* wsp1 = wstr + r1;

    float pf0, pf1;
    {
        int sp0 = d ? (S - 1) : 0;
        size_t tok = (size_t)toks[sp0];
        pf0 = pe[(tok << 10) + r0];
        pf1 = pe[(tok << 10) + r1];
    }

    for (int ss = 0; ss < S; ss++) {
        int sp = d ? (S - 1 - ss) : ss;
        float acc0 = pf0, acc1 = pf1;
        if (ss + 1 < S) {
            int spn = d ? (S - 2 - ss) : (ss + 1);
            size_t tok = (size_t)toks[spn];
            pf0 = pe[(tok << 10) + r0];
            pf1 = pe[(tok << 10) + r1];
        }

        /* "register"-W phase: cols 0..79 */
        #pragma unroll
        for (int g = 0; g < WREG; g++) {
            float4 h4 = hs4[g];
            float4 a = wA[g], bb2 = wB[g];
            acc0 = fmaf(a.x, h4.x, acc0);  acc1 = fmaf(bb2.x, h4.x, acc1);
            acc0 = fmaf(a.y, h4.y, acc0);  acc1 = fmaf(bb2.y, h4.y, acc1);
            acc0 = fmaf(a.z, h4.z, acc0);  acc1 = fmaf(bb2.z, h4.z, acc1);
            acc0 = fmaf(a.w, h4.w, acc0);  acc1 = fmaf(bb2.w, h4.w, acc1);
        }
        /* LDS-W phase: cols 80..91 */
        #pragma unroll
        for (int g = 0; g < WLDS; g++) {
            float4 w0 = sW[(g << 10) + r0];
            float4 w1 = sW[(g << 10) + r1];
            float4 h4 = hs4[WREG + g];
            acc0 = fmaf(w0.x, h4.x, acc0);  acc1 = fmaf(w1.x, h4.x, acc1);
            acc0 = fmaf(w0.y, h4.y, acc0);  acc1 = fmaf(w1.y, h4.y, acc1);
            acc0 = fmaf(w0.z, h4.z, acc0);  acc1 = fmaf(w1.z, h4.z, acc1);
            acc0 = fmaf(w0.w, h4.w, acc0);  acc1 = fmaf(w1.w, h4.w, acc1);
        }
        /* streamed phase: cols 92..255 (bounded pipelining via unroll 4) */
        #pragma unroll 4
        for (int g = 0; g < WSTR; g++) {
            float4 w0 = wsp0[(size_t)g << 10];
            float4 w1 = wsp1[(size_t)g << 10];
            float4 h4 = hs4[WREG + WLDS + g];
            acc0 = fmaf(w0.x, h4.x, acc0);  acc1 = fmaf(w1.x, h4.x, acc1);
            acc0 = fmaf(w0.y, h4.y, acc0);  acc1 = fmaf(w1.y, h4.y, acc1);
            acc0 = fmaf(w0.z, h4.z, acc0);  acc1 = fmaf(w1.z, h4.z, acc1);
            acc0 = fmaf(w0.w, h4.w, acc0);  acc1 = fmaf(w1.w, h4.w, acc1);
        }
        gbuf[r0] = acc0;
        gbuf[r1] = acc1;
        __syncthreads();   /* B1: gates complete, hs reads done */

        if (t < 256) {
            float gi = gbuf[t], gf = gbuf[H + t], gg = gbuf[2 * H + t], go = gbuf[3 * H + t];
            float ig = sigf(gi), fg = sigf(gf), tg = tanhf(gg), og = sigf(go);
            cst = fg * cst + ig * tg;
            float hn = og * tanhf(cst);
            hs[t] = hn;
            int l = t & 63, wv = t >> 6;
            #pragma unroll
            for (int tt = 0; tt < T; tt++) {
                float v = hn * mw[tt];
                v += __shfl_xor(v, 32, 64); v += __shfl_xor(v, 16, 64);
                v += __shfl_xor(v, 8, 64);  v += __shfl_xor(v, 4, 64);
                v += __shfl_xor(v, 2, 64);  v += __shfl_xor(v, 1, 64);
                if (l == 0) red[tt][wv] = v;
            }
        }
        __syncthreads();   /* B2: hs updated + red ready */
        if (t < T)
            emdst[((size_t)b * S + sp) * T + t] = red[t][0] + red[t][1] + red[t][2] + red[t][3];
    }
}

/* Viterbi forward: one wave per batch, lane t = tag. Strict-> ascending scan
   matches jnp.argmax first-index tie-breaking. */
__global__ __launch_bounds__(64) void k_vit(const int* __restrict__ data,
                                            const float* __restrict__ strans,
                                            const float* __restrict__ trans,
                                            const float* __restrict__ etrans,
                                            const float* __restrict__ mlpb,
                                            float* __restrict__ out,
                                            char* __restrict__ ws) {
    int b = blockIdx.x, t = threadIdx.x;
    const float* emf = (const float*)(ws + OFF_EMF);
    const float* emb = (const float*)(ws + OFF_EMB);
    char* bp = ws + OFF_BP;
    int*  lt = (int*)(ws + OFF_LT);
    bool act = t < T;

    float trp[T];
    float mb = 0.0f;
    if (act) {
        #pragma unroll
        for (int p = 0; p < T; p++) trp[p] = trans[p * T + t];
        mb = mlpb[t];
    }
    float score = -1e30f;
    if (act) score = strans[t] + emf[(b * S) * T + t] + emb[(b * S) * T + t] + mb;

    for (int s = 1; s < S; s++) {
        float e = 0.0f;
        if (act) e = emf[(b * S + s) * T + t] + emb[(b * S + s) * T + t] + mb;
        float best = __shfl(score, 0, 64) + trp[0];
        int bpi = 0;
        #pragma unroll
        for (int p = 1; p < T; p++) {
            float cand = __shfl(score, p, 64) + trp[p];
            if (cand > best) { best = cand; bpi = p; }
        }
        int m = data[b * S + s] != 0;
        if (act) {
            score = m ? (best + e) : score;
            bp[((size_t)(s - 1) * B + b) * 16 + t] = (char)bpi;
        }
    }
    float fin = act ? score + etrans[t] : -1e30f;
    float bv = __shfl(fin, 0, 64);
    int bi = 0;
    #pragma unroll
    for (int p = 1; p < T; p++) {
        float v = __shfl(fin, p, 64);
        if (v > bv) { bv = v; bi = p; }
    }
    if (t == 0) { out[B * S + b] = bv; lt[b] = bi; }
}

/* Backtrack: thread = batch; bp row address is tag-independent -> pipelined loads */
__global__ __launch_bounds__(128) void k_back(const int* __restrict__ data, char* __restrict__ ws) {
    int b = threadIdx.x;
    const int4* bp4 = (const int4*)(ws + OFF_BP);
    const int*  lt  = (const int*)(ws + OFF_LT);
    int* pt = (int*)(ws + OFF_PT);
    int tag = lt[b];
    pt[(S - 1) * B + b] = tag;
    for (int p = S - 2; p >= 0; p--) {
        int4 r = bp4[(size_t)p * B + b];
        int m = data[b * S + p + 1] != 0;
        unsigned w = (unsigned)(tag < 8 ? (tag < 4 ? r.x : r.y) : r.z);
        int nt = (int)((w >> ((tag & 3) * 8)) & 0xff);
        tag = m ? nt : tag;
        pt[p * B + b] = tag;
    }
}

/* paths -> float output with mask zeroing */
__global__ __launch_bounds__(256) void k_fin(const int* __restrict__ data,
                                             float* __restrict__ out,
                                             const char* __restrict__ ws) {
    int tid = blockIdx.x * 256 + threadIdx.x;   /* 65536 */
    const int* pt = (const int*)(ws + OFF_PT);
    int b = tid >> 9, p = tid & 511;
    out[tid] = (data[tid] != 0) ? (float)pt[p * B + b] : 0.0f;
}

extern "C" void kernel_launch(void* const* d_in, const int* in_sizes, int n_in,
                              void* d_out, int out_size, void* d_ws, size_t ws_size,
                              hipStream_t stream) {
    const int*   data = (const int*)d_in[0];
    /* d_in[1] = mask (bool) — unused; mask == (data != 0) */
    const float* emb  = (const float*)d_in[2];
    const float* wihf = (const float*)d_in[3];
    const float* whhf = (const float*)d_in[4];
    const float* bf   = (const float*)d_in[5];
    const float* wihb = (const float*)d_in[6];
    const float* whhb = (const float*)d_in[7];
    const float* bb   = (const float*)d_in[8];
    const float* mlpW = (const float*)d_in[9];
    const float* mlpb = (const float*)d_in[10];
    const float* st   = (const float*)d_in[11];
    const float* tr   = (const float*)d_in[12];
    const float* et   = (const float*)d_in[13];
    float* out = (float*)d_out;
    char*  ws  = (char*)d_ws;

    hipLaunchKernelGGL(k_pemb, dim3(750),  dim3(256), 0, stream, emb, wihf, bf, wihb, bb, ws);
    hipLaunchKernelGGL(k_prep, dim3(328),  dim3(256), 0, stream, whhf, whhb, ws);
    hipLaunchKernelGGL(k_lstm, dim3(256),  dim3(512), 0, stream, data, whhf, whhb, mlpW, ws);
    hipLaunchKernelGGL(k_vit,  dim3(128),  dim3(64),  0, stream, data, st, tr, et, mlpb, out, ws);
    hipLaunchKernelGGL(k_back, dim3(1),    dim3(128), 0, stream, data, ws);
    hipLaunchKernelGGL(k_fin,  dim3(256),  dim3(256), 0, stream, data, out, ws);
}